// Round 17
// baseline (188.443 us; speedup 1.0000x reference)
//
#include <hip/hip_runtime.h>
#include <hip/hip_fp16.h>
#include <math.h>

#define N_T    16384
#define N_ROWS 2048
#define M_FFT  8192
#define K_LO   410
#define K_HI   1365
#define NBAND  956   // K_HI - K_LO + 1

typedef float cf2 __attribute__((ext_vector_type(2)));  // complex as packed fp32

__device__ __forceinline__ int rev13(int k) { return (int)(__brev((unsigned)k) >> 19); }
__device__ __forceinline__ cf2 cmul(cf2 a, cf2 b) {
    return (cf2){a.x * b.x - a.y * b.y, a.x * b.y + a.y * b.x};
}
__device__ __forceinline__ __half2 pkh(cf2 a) { return __floats2half2_rn(a.x, a.y); }
__device__ __forceinline__ cf2 unpkh(__half2 h) {
    float2 f = __half22float2(h);
    return (cf2){f.x, f.y};
}

// exp(-i*pi*m/16), m=0..15
__device__ __constant__ const float TW16C[16] = {
    1.0f, 0.9807852804f, 0.9238795325f, 0.8314696123f,
    0.7071067812f, 0.5555702330f, 0.3826834324f, 0.1950903220f,
    0.0f, -0.1950903220f, -0.3826834324f, -0.5555702330f,
    -0.7071067812f, -0.8314696123f, -0.9238795325f, -0.9807852804f};
__device__ __constant__ const float TW16S[16] = {
    0.0f, -0.1950903220f, -0.3826834324f, -0.5555702330f,
    -0.7071067812f, -0.8314696123f, -0.9238795325f, -0.9807852804f,
    -1.0f, -0.9807852804f, -0.9238795325f, -0.8314696123f,
    -0.7071067812f, -0.5555702330f, -0.3826834324f, -0.1950903220f};

// Per-element stats body: identical math to the validated version.
__device__ __forceinline__ void stat_elem(int i,
    float pm2, float pm1, float p0, float pp1, float pp2,
    float tm2, float tm1, float t0, float tp1, float tp2,
    float* acc) {
    acc[0] += p0; acc[1] += p0 * p0;
    acc[2] += t0; acc[3] += t0 * t0;
    acc[4] += p0 * t0;
    float g1p, g1t, g2p, g2t;
    if (i >= 2 && i <= N_T - 3) {
        g1p = 0.5f * (pp1 - pm1); g1t = 0.5f * (tp1 - tm1);
        g2p = 0.5f * (0.5f * (pp2 - p0) - 0.5f * (p0 - pm2));
        g2t = 0.5f * (0.5f * (tp2 - t0) - 0.5f * (t0 - tm2));
    } else if (i == 0) {
        g1p = pp1 - p0;              g2p = 0.5f * (pp2 - p0) - (pp1 - p0);
        g1t = tp1 - t0;              g2t = 0.5f * (tp2 - t0) - (tp1 - t0);
    } else if (i == 1) {
        g1p = 0.5f * (pp1 - pm1);    g2p = 0.5f * (0.5f * (pp2 - p0) - (p0 - pm1));
        g1t = 0.5f * (tp1 - tm1);    g2t = 0.5f * (0.5f * (tp2 - t0) - (t0 - tm1));
    } else if (i == N_T - 2) {
        g1p = 0.5f * (pp1 - pm1);    g2p = 0.5f * ((pp1 - p0) - 0.5f * (p0 - pm2));
        g1t = 0.5f * (tp1 - tm1);    g2t = 0.5f * ((tp1 - t0) - 0.5f * (t0 - tm2));
    } else {  // i == N_T-1
        g1p = p0 - pm1;              g2p = (p0 - pm1) - 0.5f * (p0 - pm2);
        g1t = t0 - tm1;              g2t = (t0 - tm1) - 0.5f * (t0 - tm2);
    }
    acc[5] += g1p * g1t; acc[6] += g1p * g1p; acc[7] += g1t * g1t;
    acc[8] += g2p * g2t; acc[9] += g2p * g2p; acc[10] += g2t * g2t;
    if (i >= 1 && i <= N_T - 2) {
        bool mx  = (p0 > pm1) && (p0 > pp1);
        bool mn  = (p0 < pm1) && (p0 < pp1);
        bool mxt = (t0 > tm1) && (t0 > tp1);
        bool mnt = (t0 < tm1) && (t0 < tp1);
        acc[11] += mx ? 1.0f : 0.0f;
        acc[12] += mn ? 1.0f : 0.0f;
        acc[13] += mxt ? 1.0f : 0.0f;
        acc[14] += mnt ? 1.0f : 0.0f;
        acc[15] += mx ? p0 : 0.0f;
        acc[16] += mn ? p0 : 0.0f;
    }
}

// Fused role-split kernel. bid%3==2 -> stats(row=bid/3), else fft(row, arr).
// amdgpu_waves_per_eu(2,2): r15/r16 showed launch_bounds min-arg only CAPS
// VGPR (256) but the allocator still TARGETS 8 waves/EU and squeezes to 64,
// spilling the fft role's r[32] (WRITE_SIZE 360 KB). The (min,max) attribute
// pins the occupancy target at 2 waves/EU from both sides, so the allocator
// has no incentive to squeeze below its natural ~116 VGPR. Runtime occupancy
// is still set by actual usage: VGPR<=128 + LDS 33 KB -> 4 blocks/CU.
__global__ __launch_bounds__(256)
__attribute__((amdgpu_waves_per_eu(2, 2)))
void fused_kernel(const float* __restrict__ pred,
                  const float* __restrict__ targ,
                  float* __restrict__ wpear,
                  float* __restrict__ wderiv,
                  float* __restrict__ wpeak,
                  float* __restrict__ fout) {
    __shared__ __align__(16) char shraw[33792];   // 8448 half2 (fft) / red (stats)
    const int bid = blockIdx.x;
    const int trip = bid / 3, rem = bid - 3 * trip;
    const int t = threadIdx.x;

    if (rem == 2) {
        // ================= stats role (row = trip), r14 body =================
        float (*red)[17] = (float (*)[17])shraw;
        const int row = trip;
        const float* p = pred + (size_t)row * N_T;
        const float* tg = targ + (size_t)row * N_T;

        float acc[17];
#pragma unroll
        for (int q = 0; q < 17; ++q) acc[q] = 0.0f;

        for (int q = 0; q < 16; ++q) {
            int e0 = 4 * t + 1024 * q;
            float4 Cp = *(const float4*)(p + e0);
            float4 Ct = *(const float4*)(tg + e0);
            float2 Lp = make_float2(0.0f, 0.0f), Lt = make_float2(0.0f, 0.0f);
            float2 Rp = make_float2(0.0f, 0.0f), Rt = make_float2(0.0f, 0.0f);
            if (e0 > 0) {
                Lp = *(const float2*)(p + e0 - 2);
                Lt = *(const float2*)(tg + e0 - 2);
            }
            if (e0 + 4 < N_T) {
                Rp = *(const float2*)(p + e0 + 4);
                Rt = *(const float2*)(tg + e0 + 4);
            }
            stat_elem(e0 + 0, Lp.x, Lp.y, Cp.x, Cp.y, Cp.z,
                              Lt.x, Lt.y, Ct.x, Ct.y, Ct.z, acc);
            stat_elem(e0 + 1, Lp.y, Cp.x, Cp.y, Cp.z, Cp.w,
                              Lt.y, Ct.x, Ct.y, Ct.z, Ct.w, acc);
            stat_elem(e0 + 2, Cp.x, Cp.y, Cp.z, Cp.w, Rp.x,
                              Ct.x, Ct.y, Ct.z, Ct.w, Rt.x, acc);
            stat_elem(e0 + 3, Cp.y, Cp.z, Cp.w, Rp.x, Rp.y,
                              Ct.y, Ct.z, Ct.w, Rt.x, Rt.y, acc);
        }

        int lane = t & 63, wv = t >> 6;
#pragma unroll
        for (int q = 0; q < 17; ++q) {
            float v = acc[q];
            for (int off = 1; off < 64; off <<= 1) v += __shfl_xor(v, off);
            if (lane == 0) red[wv][q] = v;
        }
        __syncthreads();
        if (t == 0) {
            float a[17];
#pragma unroll
            for (int q = 0; q < 17; ++q) a[q] = red[0][q] + red[1][q] + red[2][q] + red[3][q];
            const float Nf = (float)N_T;
            float cov = a[4] - a[0] * a[2] / Nf;
            float vp  = a[1] - a[0] * a[0] / Nf;
            float vt  = a[3] - a[2] * a[2] / Nf;
            float r   = cov / sqrtf(vp * vt);
            float c1  = a[5] / sqrtf(a[6] * a[7]);
            float c2  = a[8] / sqrtf(a[9] * a[10]);
            float cntd  = fabsf(a[13] - a[11]);
            float ncntd = fabsf(a[14] - a[12]);
            float vald  = fabsf(1.0f - a[15] / a[11]);
            float nvald = fabsf(1.0f - a[16] / a[12]);
            wpear[row]  = 1.0f - r;
            wderiv[row] = c1 + c2;
            wpeak[row]  = 0.5f * (cntd + ncntd + vald + nvald);
        }
        return;
    }

    // ================= fft role (row = trip, arr = rem), r14 body =================
    __half2* zh = (__half2*)shraw;
    cf2*     zf = (cf2*)shraw;       // cf2 overlay for band phase (1912 used)
    const int row = trip, arr = rem;
    const cf2* __restrict__ x = (const cf2*)((arr ? targ : pred) + (size_t)row * N_T);

    cf2 r[32];
#pragma unroll
    for (int m = 0; m < 32; ++m) r[m] = x[t + 256 * m];

    // ---- phase 1: DIF stages h = 4096..256; twiddles hoisted (31 cmuls) ----
#pragma unroll
    for (int p = 0; p < 5; ++p) {
        const int d = 16 >> p;
        float s0, c0;
        __sincosf((float)M_PI * (float)t / (float)(256 * d), &s0, &c0);
        const cf2 wbase = {c0, -s0};
        cf2 cwt[16];
#pragma unroll
        for (int j = 0; j < d; ++j)
            cwt[j] = cmul(wbase, (cf2){TW16C[j * (16 / d)], TW16S[j * (16 / d)]});
#pragma unroll
        for (int m = 0; m < 32; ++m) {
            if ((m & d) == 0) {
                cf2 a = r[m], b = r[m + d];
                r[m] = a + b;                       // v_pk_add_f32
                r[m + d] = cmul(a - b, cwt[m & (d - 1)]);
            }
        }
    }

    // ---- transpose 1 (fp16, padded stride 258): (t + 256m) -> (256bb + cc + 8w)
    const int bb = t >> 3, cc = t & 7;
#pragma unroll
    for (int m = 0; m < 32; ++m) zh[258 * m + t] = pkh(r[m]);       // imm offset 258m
    __syncthreads();
    const int rb1 = 258 * bb + cc;                                   // per-thread base
#pragma unroll
    for (int w = 0; w < 32; ++w) r[w] = unpkh(zh[rb1 + 8 * w]);      // imm offset 8w

    // ---- phase 2: DIF stages h = 128..8; twiddles hoisted ----
#pragma unroll
    for (int p = 0; p < 5; ++p) {
        const int d = 16 >> p;
        float s0, c0;
        __sincosf((float)M_PI * (float)cc / (float)(8 * d), &s0, &c0);
        const cf2 wbase = {c0, -s0};
        cf2 cwt[16];
#pragma unroll
        for (int j = 0; j < d; ++j)
            cwt[j] = cmul(wbase, (cf2){TW16C[j * (16 / d)], TW16S[j * (16 / d)]});
#pragma unroll
        for (int w = 0; w < 32; ++w) {
            if ((w & d) == 0) {
                cf2 a = r[w], b = r[w + d];
                r[w] = a + b;
                r[w + d] = cmul(a - b, cwt[w & (d - 1)]);
            }
        }
    }

    // ---- transpose 2 (fp16, pad addr = j + (j>>5)): (256bb+cc+8w) -> (32t+v)
    __syncthreads();  // all T1 reads done before overwrite
    const int wb2 = 264 * bb + cc;                                   // per-thread base
#pragma unroll
    for (int w = 0; w < 32; ++w)
        zh[wb2 + 8 * w + (w >> 2)] = pkh(r[w]);                      // imm offset
    __syncthreads();
    const int rb2 = 33 * t;                                          // per-thread base
#pragma unroll
    for (int v = 0; v < 32; ++v) r[v] = unpkh(zh[rb2 + v]);          // imm offset v

    // ---- phase 3: h = 4,2,1 register-internal, compile-time twiddles ----
#pragma unroll
    for (int v = 0; v < 32; ++v) {
        if ((v & 4) == 0) {
            const int s = v & 3;
            const cf2 tw = {TW16C[4 * s], TW16S[4 * s]};
            cf2 a = r[v], b = r[v + 4];
            r[v] = a + b;
            r[v + 4] = cmul(a - b, tw);
        }
    }
#pragma unroll
    for (int v = 0; v < 32; ++v) {
        if ((v & 2) == 0) {
            cf2 a = r[v], b = r[v + 2];
            r[v] = a + b;
            cf2 df = a - b;
            r[v + 2] = (v & 1) ? (cf2){df.y, -df.x} : df;  // *(-i) if odd
        }
    }
#pragma unroll
    for (int v = 0; v < 32; ++v) {
        if ((v & 1) == 0) {
            cf2 a = r[v], b = r[v + 1];
            r[v] = a + b;
            r[v + 1] = a - b;
        }
    }

    // ---- band-restricted store (fp32): position i = 32t+v holds k = rev13(i) ----
    __syncthreads();  // all T2 reads done before overwrite
#pragma unroll
    for (int v = 0; v < 32; ++v) {
        int i = 32 * t + v;
        int k = rev13(i);
        if (k >= K_LO && k <= K_HI) zf[k - K_LO] = r[v];                    // A-side
        else if (k >= M_FFT - K_HI && k <= M_FFT - K_LO)
            zf[NBAND + (M_FFT - K_LO) - k] = r[v];                          // B-side
    }
    __syncthreads();

    // ---- combine to rfft bins in band, argmax (tie -> lowest k) ----
    float sb, cb2;
    __sincosf((float)M_PI * (float)(K_LO + t) / 8192.0f, &sb, &cb2);
    const cf2 wb = {cb2, -sb};
    const cf2 TWJ[4] = {
        {1.0f, 0.0f},
        {0.9951847267f, -0.0980171403f},
        {0.9807852804f, -0.1950903220f},
        {0.9569403357f, -0.2902846773f}};
    float bestp = -1.0f;
    int bestk = 1 << 30;
#pragma unroll
    for (int j = 0; j < 4; ++j) {
        int k = K_LO + t + 256 * j;
        if (k <= K_HI) {
            cf2 A = zf[k - K_LO];
            cf2 B = zf[NBAND + (k - K_LO)];
            float Er = 0.5f * (A.x + B.x), Ei = 0.5f * (A.y - B.y);
            float Or = 0.5f * (A.y + B.y), Oi = 0.5f * (B.x - A.x);
            cf2 W = cmul(wb, TWJ[j]);
            float Xr = Er + W.x * Or + (-W.y) * Oi;
            float Xi = Ei + W.x * Oi - (-W.y) * Or;
            float p = Xr * Xr + Xi * Xi;
            if (p > bestp) { bestp = p; bestk = k; }
        }
    }
    for (int off = 1; off < 64; off <<= 1) {
        float op = __shfl_xor(bestp, off);
        int   ok = __shfl_xor(bestk, off);
        if (op > bestp || (op == bestp && ok < bestk)) { bestp = op; bestk = ok; }
    }
    __syncthreads();  // all band reads done; reuse zf[0..3]
    if ((t & 63) == 0) zf[t >> 6] = (cf2){bestp, (float)bestk};
    __syncthreads();
    if (t == 0) {
        for (int wv = 0; wv < 4; ++wv) {
            cf2 rr = zf[wv];
            int ok = (int)rr.y;
            if (rr.x > bestp || (rr.x == bestp && ok < bestk)) { bestp = rr.x; bestk = ok; }
        }
        fout[arr * N_ROWS + row] = (float)bestk * (30.0f / 16384.0f);
    }
}

__global__ __launch_bounds__(256) void reduce_kernel(const float* __restrict__ wpear,
                                                     const float* __restrict__ wderiv,
                                                     const float* __restrict__ wpeak,
                                                     const float* __restrict__ fout,
                                                     float* __restrict__ out) {
    __shared__ float red[4][3];
    int tid = threadIdx.x;
    float s1 = 0.0f, s2 = 0.0f, s3 = 0.0f;
    for (int r = tid; r < N_ROWS; r += 256) {
        s1 += wpear[r];
        s2 += wderiv[r];
        s3 += wpeak[r] + fabsf(fout[N_ROWS + r] - fout[r]);
    }
    int lane = tid & 63, wv = tid >> 6;
    for (int off = 1; off < 64; off <<= 1) {
        s1 += __shfl_xor(s1, off);
        s2 += __shfl_xor(s2, off);
        s3 += __shfl_xor(s3, off);
    }
    if (lane == 0) { red[wv][0] = s1; red[wv][1] = s2; red[wv][2] = s3; }
    __syncthreads();
    if (tid == 0) {
        float a = 0.0f, b = 0.0f, cc = 0.0f;
        for (int w = 0; w < 4; ++w) { a += red[w][0]; b += red[w][1]; cc += red[w][2]; }
        const float Nf = (float)N_ROWS;
        float res = a / Nf + cc / Nf + (2.0f - b / Nf);
        out[0] = res;  // reference output dtype is float32
    }
}

extern "C" void kernel_launch(void* const* d_in, const int* in_sizes, int n_in,
                              void* d_out, int out_size, void* d_ws, size_t ws_size,
                              hipStream_t stream) {
    const float* pred = (const float*)d_in[0];
    const float* targ = (const float*)d_in[1];
    float* ws = (float*)d_ws;
    float* wpear  = ws;             // 2048
    float* wderiv = ws + 2048;      // 2048
    float* wpeak  = ws + 4096;      // 2048
    float* fout   = ws + 6144;      // 4096 (pred freqs, then targ freqs)

    fused_kernel<<<3 * N_ROWS, 256, 0, stream>>>(pred, targ, wpear, wderiv, wpeak, fout);
    reduce_kernel<<<1, 256, 0, stream>>>(wpear, wderiv, wpeak, fout, (float*)d_out);
}

// Round 18
// 121.956 us; speedup vs baseline: 1.5452x; 1.5452x over previous
//
#include <hip/hip_runtime.h>
#include <hip/hip_fp16.h>
#include <math.h>

#define N_T    16384
#define N_ROWS 2048
#define M_FFT  8192
#define K_LO   410
#define K_HI   1365
#define NBAND  956   // K_HI - K_LO + 1

typedef float cf2 __attribute__((ext_vector_type(2)));  // complex as packed fp32

__device__ __forceinline__ int rev13(int k) { return (int)(__brev((unsigned)k) >> 19); }
__device__ __forceinline__ cf2 cmul(cf2 a, cf2 b) {
    return (cf2){a.x * b.x - a.y * b.y, a.x * b.y + a.y * b.x};
}

__device__ __forceinline__ __half2 pkh(cf2 a) { return __floats2half2_rn(a.x, a.y); }
__device__ __forceinline__ cf2 unpkh(__half2 h) {
    float2 f = __half22float2(h);
    return (cf2){f.x, f.y};
}

// exp(-i*pi*m/16), m=0..15
__device__ __constant__ const float TW16C[16] = {
    1.0f, 0.9807852804f, 0.9238795325f, 0.8314696123f,
    0.7071067812f, 0.5555702330f, 0.3826834324f, 0.1950903220f,
    0.0f, -0.1950903220f, -0.3826834324f, -0.5555702330f,
    -0.7071067812f, -0.8314696123f, -0.9238795325f, -0.9807852804f};
__device__ __constant__ const float TW16S[16] = {
    0.0f, -0.1950903220f, -0.3826834324f, -0.5555702330f,
    -0.7071067812f, -0.8314696123f, -0.9238795325f, -0.9807852804f,
    -1.0f, -0.9807852804f, -0.9238795325f, -0.8314696123f,
    -0.7071067812f, -0.5555702330f, -0.3826834324f, -0.1950903220f};

// One workgroup per (row, array). 8192-pt packed-complex FFT (r14 best config):
// 5 register stages (hoisted twiddles), padded-layout T1, 5 register stages,
// padded-layout T2, 3 register stages (const twiddles), band-restricted store,
// band argmax. Transposes carry fp16 (33 KB -> 4 blocks/CU); all math fp32.
// Padded layouts make every LDS access per-thread-base + compile-time imm
// offset (no per-access address VALU). T1: element i at (i>>8)*258 + (i&255);
// T2: element j at j + (j>>5). Both 4 lanes/bank-pair (minimal) on both sides.
__global__ __launch_bounds__(256) void fft_kernel(const float* __restrict__ pred,
                                                  const float* __restrict__ targ,
                                                  float* __restrict__ fout) {
    __shared__ __align__(16) char shraw[33792];   // 8448 half2
    __half2* zh = (__half2*)shraw;
    cf2*     zf = (cf2*)shraw;       // cf2 overlay for band phase (1912 used)
    const int wg = blockIdx.x;
    const int row = wg >> 1, arr = wg & 1;
    const cf2* __restrict__ x = (const cf2*)((arr ? targ : pred) + (size_t)row * N_T);
    const int t = threadIdx.x;

    cf2 r[32];
#pragma unroll
    for (int m = 0; m < 32; ++m) r[m] = x[t + 256 * m];

    // ---- phase 1: DIF stages h = 4096..256; twiddles hoisted (31 cmuls) ----
#pragma unroll
    for (int p = 0; p < 5; ++p) {
        const int d = 16 >> p;
        float s0, c0;
        __sincosf((float)M_PI * (float)t / (float)(256 * d), &s0, &c0);
        const cf2 wbase = {c0, -s0};
        cf2 cwt[16];
#pragma unroll
        for (int j = 0; j < d; ++j)
            cwt[j] = cmul(wbase, (cf2){TW16C[j * (16 / d)], TW16S[j * (16 / d)]});
#pragma unroll
        for (int m = 0; m < 32; ++m) {
            if ((m & d) == 0) {
                cf2 a = r[m], b = r[m + d];
                r[m] = a + b;                       // v_pk_add_f32
                r[m + d] = cmul(a - b, cwt[m & (d - 1)]);
            }
        }
    }

    // ---- transpose 1 (fp16, padded stride 258): (t + 256m) -> (256bb + cc + 8w)
    const int bb = t >> 3, cc = t & 7;
#pragma unroll
    for (int m = 0; m < 32; ++m) zh[258 * m + t] = pkh(r[m]);       // imm offset 258m
    __syncthreads();
    const int rb1 = 258 * bb + cc;                                   // per-thread base
#pragma unroll
    for (int w = 0; w < 32; ++w) r[w] = unpkh(zh[rb1 + 8 * w]);      // imm offset 8w

    // ---- phase 2: DIF stages h = 128..8; twiddles hoisted ----
#pragma unroll
    for (int p = 0; p < 5; ++p) {
        const int d = 16 >> p;
        float s0, c0;
        __sincosf((float)M_PI * (float)cc / (float)(8 * d), &s0, &c0);
        const cf2 wbase = {c0, -s0};
        cf2 cwt[16];
#pragma unroll
        for (int j = 0; j < d; ++j)
            cwt[j] = cmul(wbase, (cf2){TW16C[j * (16 / d)], TW16S[j * (16 / d)]});
#pragma unroll
        for (int w = 0; w < 32; ++w) {
            if ((w & d) == 0) {
                cf2 a = r[w], b = r[w + d];
                r[w] = a + b;
                r[w + d] = cmul(a - b, cwt[w & (d - 1)]);
            }
        }
    }

    // ---- transpose 2 (fp16, pad addr = j + (j>>5)): (256bb+cc+8w) -> (32t+v)
    __syncthreads();  // all T1 reads done before overwrite
    const int wb2 = 264 * bb + cc;                                   // per-thread base
#pragma unroll
    for (int w = 0; w < 32; ++w)
        zh[wb2 + 8 * w + (w >> 2)] = pkh(r[w]);                      // imm offset
    __syncthreads();
    const int rb2 = 33 * t;                                          // per-thread base
#pragma unroll
    for (int v = 0; v < 32; ++v) r[v] = unpkh(zh[rb2 + v]);          // imm offset v

    // ---- phase 3: h = 4,2,1 register-internal, compile-time twiddles ----
#pragma unroll
    for (int v = 0; v < 32; ++v) {
        if ((v & 4) == 0) {
            const int s = v & 3;
            const cf2 tw = {TW16C[4 * s], TW16S[4 * s]};
            cf2 a = r[v], b = r[v + 4];
            r[v] = a + b;
            r[v + 4] = cmul(a - b, tw);
        }
    }
#pragma unroll
    for (int v = 0; v < 32; ++v) {
        if ((v & 2) == 0) {
            cf2 a = r[v], b = r[v + 2];
            r[v] = a + b;
            cf2 df = a - b;
            r[v + 2] = (v & 1) ? (cf2){df.y, -df.x} : df;  // *(-i) if odd
        }
    }
#pragma unroll
    for (int v = 0; v < 32; ++v) {
        if ((v & 1) == 0) {
            cf2 a = r[v], b = r[v + 1];
            r[v] = a + b;
            r[v + 1] = a - b;
        }
    }

    // ---- band-restricted store (fp32): position i = 32t+v holds k = rev13(i) ----
    __syncthreads();  // all T2 reads done before overwrite
#pragma unroll
    for (int v = 0; v < 32; ++v) {
        int i = 32 * t + v;
        int k = rev13(i);
        if (k >= K_LO && k <= K_HI) zf[k - K_LO] = r[v];                    // A-side
        else if (k >= M_FFT - K_HI && k <= M_FFT - K_LO)
            zf[NBAND + (M_FFT - K_LO) - k] = r[v];                          // B-side
    }
    __syncthreads();

    // ---- combine to rfft bins in band, argmax (tie -> lowest k) ----
    float sb, cb2;
    __sincosf((float)M_PI * (float)(K_LO + t) / 8192.0f, &sb, &cb2);
    const cf2 wb = {cb2, -sb};
    const cf2 TWJ[4] = {
        {1.0f, 0.0f},
        {0.9951847267f, -0.0980171403f},
        {0.9807852804f, -0.1950903220f},
        {0.9569403357f, -0.2902846773f}};
    float bestp = -1.0f;
    int bestk = 1 << 30;
#pragma unroll
    for (int j = 0; j < 4; ++j) {
        int k = K_LO + t + 256 * j;
        if (k <= K_HI) {
            cf2 A = zf[k - K_LO];
            cf2 B = zf[NBAND + (k - K_LO)];
            float Er = 0.5f * (A.x + B.x), Ei = 0.5f * (A.y - B.y);
            float Or = 0.5f * (A.y + B.y), Oi = 0.5f * (B.x - A.x);
            cf2 W = cmul(wb, TWJ[j]);
            float Xr = Er + W.x * Or + (-W.y) * Oi;
            float Xi = Ei + W.x * Oi - (-W.y) * Or;
            float p = Xr * Xr + Xi * Xi;
            if (p > bestp) { bestp = p; bestk = k; }
        }
    }
    for (int off = 1; off < 64; off <<= 1) {
        float op = __shfl_xor(bestp, off);
        int   ok = __shfl_xor(bestk, off);
        if (op > bestp || (op == bestp && ok < bestk)) { bestp = op; bestk = ok; }
    }
    __syncthreads();  // all band reads done; reuse zf[0..3]
    if ((t & 63) == 0) zf[t >> 6] = (cf2){bestp, (float)bestk};
    __syncthreads();
    if (t == 0) {
        for (int wv = 0; wv < 4; ++wv) {
            cf2 rr = zf[wv];
            int ok = (int)rr.y;
            if (rr.x > bestp || (rr.x == bestp && ok < bestk)) { bestp = rr.x; bestk = ok; }
        }
        fout[arr * N_ROWS + row] = (float)bestk * (30.0f / 16384.0f);
    }
}

// Per-element stats body: identical math to the validated version.
__device__ __forceinline__ void stat_elem(int i,
    float pm2, float pm1, float p0, float pp1, float pp2,
    float tm2, float tm1, float t0, float tp1, float tp2,
    float* acc) {
    acc[0] += p0; acc[1] += p0 * p0;
    acc[2] += t0; acc[3] += t0 * t0;
    acc[4] += p0 * t0;
    float g1p, g1t, g2p, g2t;
    if (i >= 2 && i <= N_T - 3) {
        g1p = 0.5f * (pp1 - pm1); g1t = 0.5f * (tp1 - tm1);
        g2p = 0.5f * (0.5f * (pp2 - p0) - 0.5f * (p0 - pm2));
        g2t = 0.5f * (0.5f * (tp2 - t0) - 0.5f * (t0 - tm2));
    } else if (i == 0) {
        g1p = pp1 - p0;              g2p = 0.5f * (pp2 - p0) - (pp1 - p0);
        g1t = tp1 - t0;              g2t = 0.5f * (tp2 - t0) - (tp1 - t0);
    } else if (i == 1) {
        g1p = 0.5f * (pp1 - pm1);    g2p = 0.5f * (0.5f * (pp2 - p0) - (p0 - pm1));
        g1t = 0.5f * (tp1 - tm1);    g2t = 0.5f * (0.5f * (tp2 - t0) - (t0 - tm1));
    } else if (i == N_T - 2) {
        g1p = 0.5f * (pp1 - pm1);    g2p = 0.5f * ((pp1 - p0) - 0.5f * (p0 - pm2));
        g1t = 0.5f * (tp1 - tm1);    g2t = 0.5f * ((tp1 - t0) - 0.5f * (t0 - tm2));
    } else {  // i == N_T-1
        g1p = p0 - pm1;              g2p = (p0 - pm1) - 0.5f * (p0 - pm2);
        g1t = t0 - tm1;              g2t = (t0 - tm1) - 0.5f * (t0 - tm2);
    }
    acc[5] += g1p * g1t; acc[6] += g1p * g1p; acc[7] += g1t * g1t;
    acc[8] += g2p * g2t; acc[9] += g2p * g2p; acc[10] += g2t * g2t;
    if (i >= 1 && i <= N_T - 2) {
        bool mx  = (p0 > pm1) && (p0 > pp1);
        bool mn  = (p0 < pm1) && (p0 < pp1);
        bool mxt = (t0 > tm1) && (t0 > tp1);
        bool mnt = (t0 < tm1) && (t0 < tp1);
        acc[11] += mx ? 1.0f : 0.0f;
        acc[12] += mn ? 1.0f : 0.0f;
        acc[13] += mxt ? 1.0f : 0.0f;
        acc[14] += mnt ? 1.0f : 0.0f;
        acc[15] += mx ? p0 : 0.0f;
        acc[16] += mn ? p0 : 0.0f;
    }
}

// One workgroup per row: pure streaming (r9/r12/r14 best form, ~85% of HBM roof).
__global__ __launch_bounds__(256) void stats_kernel(const float* __restrict__ pred,
                                                    const float* __restrict__ targ,
                                                    float* __restrict__ wpear,
                                                    float* __restrict__ wderiv,
                                                    float* __restrict__ wpeak) {
    __shared__ float red[4][17];
    int row = blockIdx.x, tid = threadIdx.x;
    const float* p = pred + (size_t)row * N_T;
    const float* t = targ + (size_t)row * N_T;

    float acc[17];
#pragma unroll
    for (int q = 0; q < 17; ++q) acc[q] = 0.0f;

    for (int q = 0; q < 16; ++q) {
        int e0 = 4 * tid + 1024 * q;
        float4 Cp = *(const float4*)(p + e0);
        float4 Ct = *(const float4*)(t + e0);
        float2 Lp = make_float2(0.0f, 0.0f), Lt = make_float2(0.0f, 0.0f);
        float2 Rp = make_float2(0.0f, 0.0f), Rt = make_float2(0.0f, 0.0f);
        if (e0 > 0) {
            Lp = *(const float2*)(p + e0 - 2);
            Lt = *(const float2*)(t + e0 - 2);
        }
        if (e0 + 4 < N_T) {
            Rp = *(const float2*)(p + e0 + 4);
            Rt = *(const float2*)(t + e0 + 4);
        }
        stat_elem(e0 + 0, Lp.x, Lp.y, Cp.x, Cp.y, Cp.z,
                          Lt.x, Lt.y, Ct.x, Ct.y, Ct.z, acc);
        stat_elem(e0 + 1, Lp.y, Cp.x, Cp.y, Cp.z, Cp.w,
                          Lt.y, Ct.x, Ct.y, Ct.z, Ct.w, acc);
        stat_elem(e0 + 2, Cp.x, Cp.y, Cp.z, Cp.w, Rp.x,
                          Ct.x, Ct.y, Ct.z, Ct.w, Rt.x, acc);
        stat_elem(e0 + 3, Cp.y, Cp.z, Cp.w, Rp.x, Rp.y,
                          Ct.y, Ct.z, Ct.w, Rt.x, Rt.y, acc);
    }

    int lane = tid & 63, wv = tid >> 6;
#pragma unroll
    for (int q = 0; q < 17; ++q) {
        float v = acc[q];
        for (int off = 1; off < 64; off <<= 1) v += __shfl_xor(v, off);
        if (lane == 0) red[wv][q] = v;
    }
    __syncthreads();
    if (tid == 0) {
        float a[17];
#pragma unroll
        for (int q = 0; q < 17; ++q) a[q] = red[0][q] + red[1][q] + red[2][q] + red[3][q];
        const float Nf = (float)N_T;
        float cov = a[4] - a[0] * a[2] / Nf;
        float vp  = a[1] - a[0] * a[0] / Nf;
        float vt  = a[3] - a[2] * a[2] / Nf;
        float r   = cov / sqrtf(vp * vt);
        float c1  = a[5] / sqrtf(a[6] * a[7]);
        float c2  = a[8] / sqrtf(a[9] * a[10]);
        float cntd  = fabsf(a[13] - a[11]);
        float ncntd = fabsf(a[14] - a[12]);
        float vald  = fabsf(1.0f - a[15] / a[11]);
        float nvald = fabsf(1.0f - a[16] / a[12]);
        wpear[row]  = 1.0f - r;
        wderiv[row] = c1 + c2;
        wpeak[row]  = 0.5f * (cntd + ncntd + vald + nvald);
    }
}

__global__ __launch_bounds__(256) void reduce_kernel(const float* __restrict__ wpear,
                                                     const float* __restrict__ wderiv,
                                                     const float* __restrict__ wpeak,
                                                     const float* __restrict__ fout,
                                                     float* __restrict__ out) {
    __shared__ float red[4][3];
    int tid = threadIdx.x;
    float s1 = 0.0f, s2 = 0.0f, s3 = 0.0f;
    for (int r = tid; r < N_ROWS; r += 256) {
        s1 += wpear[r];
        s2 += wderiv[r];
        s3 += wpeak[r] + fabsf(fout[N_ROWS + r] - fout[r]);
    }
    int lane = tid & 63, wv = tid >> 6;
    for (int off = 1; off < 64; off <<= 1) {
        s1 += __shfl_xor(s1, off);
        s2 += __shfl_xor(s2, off);
        s3 += __shfl_xor(s3, off);
    }
    if (lane == 0) { red[wv][0] = s1; red[wv][1] = s2; red[wv][2] = s3; }
    __syncthreads();
    if (tid == 0) {
        float a = 0.0f, b = 0.0f, cc = 0.0f;
        for (int w = 0; w < 4; ++w) { a += red[w][0]; b += red[w][1]; cc += red[w][2]; }
        const float Nf = (float)N_ROWS;
        float res = a / Nf + cc / Nf + (2.0f - b / Nf);
        out[0] = res;  // reference output dtype is float32
    }
}

extern "C" void kernel_launch(void* const* d_in, const int* in_sizes, int n_in,
                              void* d_out, int out_size, void* d_ws, size_t ws_size,
                              hipStream_t stream) {
    const float* pred = (const float*)d_in[0];
    const float* targ = (const float*)d_in[1];
    float* ws = (float*)d_ws;
    float* wpear  = ws;             // 2048
    float* wderiv = ws + 2048;      // 2048
    float* wpeak  = ws + 4096;      // 2048
    float* fout   = ws + 6144;      // 4096 (pred freqs, then targ freqs)

    stats_kernel<<<N_ROWS, 256, 0, stream>>>(pred, targ, wpear, wderiv, wpeak);
    fft_kernel<<<2 * N_ROWS, 256, 0, stream>>>(pred, targ, fout);
    reduce_kernel<<<1, 256, 0, stream>>>(wpear, wderiv, wpeak, fout, (float*)d_out);
}